// Round 1
// baseline (1665.813 us; speedup 1.0000x reference)
//
#include <hip/hip_runtime.h>
#include <stdint.h>

// ---------- types ----------
typedef _Float16 f16;
typedef _Float16 f16x8 __attribute__((ext_vector_type(8)));
typedef _Float16 f16x4 __attribute__((ext_vector_type(4)));
typedef float    f32x4 __attribute__((ext_vector_type(4)));

#define B_DIM 2048
#define N_DIM 65536
#define H_DIM 1024

__device__ __forceinline__ unsigned short f32_to_bf16(float f) {
    unsigned int u = __builtin_bit_cast(unsigned int, f);
    unsigned int r = u + 0x7fffu + ((u >> 16) & 1u);
    return (unsigned short)(r >> 16);
}

typedef const __attribute__((address_space(1))) void g_void;
typedef __attribute__((address_space(3))) void l_void;
__device__ __forceinline__ void glds16(const void* g, void* l) {
    __builtin_amdgcn_global_load_lds((g_void*)g, (l_void*)l, 16, 0, 0);
}

// ---------- small prep kernels ----------
__global__ __launch_bounds__(256) void k_weights(const float* __restrict__ imp,
                                                 const float* __restrict__ ts,
                                                 float* __restrict__ w,
                                                 float* __restrict__ sumw) {
    int i = blockIdx.x * 256 + threadIdx.x;
    float age = 1.0f - ts[i];
    float r = expf(-fabsf(age) * (float)(1.0 - 0.99));
    float wv = r * (imp[i] + 1.0f);
    w[i] = wv;
    for (int off = 32; off; off >>= 1) wv += __shfl_down(wv, off, 64);
    __shared__ float ps[4];
    if ((threadIdx.x & 63) == 0) ps[threadIdx.x >> 6] = wv;
    __syncthreads();
    if (threadIdx.x == 0) atomicAdd(sumw, ps[0] + ps[1] + ps[2] + ps[3]);
}

// split fp32 -> fp16 hi + fp16 lo (one float4 per thread)
__global__ __launch_bounds__(256) void k_split(const float* __restrict__ x,
                                               f16* __restrict__ hi, f16* __restrict__ lo) {
    size_t i4 = (size_t)blockIdx.x * 256 + threadIdx.x;
    float4 v = ((const float4*)x)[i4];
    f16x4 h, l;
    h[0] = (f16)v.x; l[0] = (f16)(v.x - (float)h[0]);
    h[1] = (f16)v.y; l[1] = (f16)(v.y - (float)h[1]);
    h[2] = (f16)v.z; l[2] = (f16)(v.z - (float)h[2]);
    h[3] = (f16)v.w; l[3] = (f16)(v.w - (float)h[3]);
    ((f16x4*)hi)[i4] = h;
    ((f16x4*)lo)[i4] = l;
}

__global__ __launch_bounds__(256) void k_tohalf(const float* __restrict__ x, f16* __restrict__ h) {
    size_t i4 = (size_t)blockIdx.x * 256 + threadIdx.x;
    float4 v = ((const float4*)x)[i4];
    f16x4 o = {(f16)v.x, (f16)v.y, (f16)v.z, (f16)v.w};
    ((f16x4*)h)[i4] = o;
}

// q row-normalize -> fp32 + fp16
__global__ __launch_bounds__(256) void k_qnorm(const float* __restrict__ q,
                                               float* __restrict__ qn, f16* __restrict__ q16) {
    int b = blockIdx.x, t = threadIdx.x;
    float4 v = ((const float4*)(q + (size_t)b * H_DIM))[t];
    float ss = v.x * v.x + v.y * v.y + v.z * v.z + v.w * v.w;
    for (int off = 32; off; off >>= 1) ss += __shfl_down(ss, off, 64);
    __shared__ float ps[4];
    if ((t & 63) == 0) ps[t >> 6] = ss;
    __syncthreads();
    float tot = ps[0] + ps[1] + ps[2] + ps[3];
    float rn = 1.0f / fmaxf(sqrtf(tot), 1e-12f);
    float4 o;
    o.x = v.x * rn; o.y = v.y * rn; o.z = v.z * rn; o.w = v.w * rn;
    ((float4*)(qn + (size_t)b * H_DIM))[t] = o;
    f16x4 h = {(f16)o.x, (f16)o.y, (f16)o.z, (f16)o.w};
    ((f16x4*)(q16 + (size_t)b * H_DIM))[t] = h;
}

// per-key-row: sscale[n] = w[n] / ((sumw+1e-8) * max(||keys_n||,1e-12))
__global__ __launch_bounds__(256) void k_rowstats(const float* __restrict__ keys,
                                                  const float* __restrict__ w,
                                                  const float* __restrict__ sumw,
                                                  float* __restrict__ sscale) {
    int n = blockIdx.x, t = threadIdx.x;
    float4 v = ((const float4*)(keys + (size_t)n * H_DIM))[t];
    float ss = v.x * v.x + v.y * v.y + v.z * v.z + v.w * v.w;
    for (int off = 32; off; off >>= 1) ss += __shfl_down(ss, off, 64);
    __shared__ float ps[4];
    if ((t & 63) == 0) ps[t >> 6] = ss;
    __syncthreads();
    if (t == 0) {
        float tot = ps[0] + ps[1] + ps[2] + ps[3];
        sscale[n] = w[n] / ((sumw[0] + 1e-8f) * fmaxf(sqrtf(tot), 1e-12f));
    }
}

// ---------- GEMM: C[M,N] = A[M,K] * B[N,K]^T ; 128x128 tile, 4 waves, 16x16x32 f16 MFMA ----------
// OUTMODE 0: write fp32 + fp16      (keys)
// OUTMODE 1: write bf16 of v*colscale[col]  (sim)
// OUTMODE 2: write fp16             (t)
// OUTMODE 3: write fp32             (final out)
template <bool SPLIT, int OUTMODE>
__global__ __launch_bounds__(256) void k_gemm(const f16* __restrict__ Ah, const f16* __restrict__ Al,
                                              const f16* __restrict__ Bh, const f16* __restrict__ Bl,
                                              const int K,
                                              float* __restrict__ of32, f16* __restrict__ of16,
                                              unsigned short* __restrict__ obf16,
                                              const float* __restrict__ colscale,
                                              const int N) {
    __shared__ f16 As[128 * 32];
    __shared__ f16 Bs[128 * 32];
    __shared__ f16 AsL[128 * 32];
    __shared__ f16 BsL[128 * 32];

    const int tid = threadIdx.x;
    const int m0 = blockIdx.y * 128, n0 = blockIdx.x * 128;
    const int r = tid >> 2, c8 = (tid & 3) * 8;

    const f16* ga0 = Ah + (size_t)(m0 + r) * K + c8;
    const f16* ga1 = Ah + (size_t)(m0 + r + 64) * K + c8;
    const f16* gb0 = Bh + (size_t)(n0 + r) * K + c8;
    const f16* gb1 = Bh + (size_t)(n0 + r + 64) * K + c8;
    const f16 *gal0 = nullptr, *gal1 = nullptr, *gbl0 = nullptr, *gbl1 = nullptr;
    if constexpr (SPLIT) {
        gal0 = Al + (size_t)(m0 + r) * K + c8;
        gal1 = Al + (size_t)(m0 + r + 64) * K + c8;
        gbl0 = Bl + (size_t)(n0 + r) * K + c8;
        gbl1 = Bl + (size_t)(n0 + r + 64) * K + c8;
    }

    const int lane = tid & 63, wave = tid >> 6;
    const int wm = (wave >> 1) * 64, wn = (wave & 1) * 64;
    const int q4 = lane >> 4, m16 = lane & 15;
    const int aoff = (wm + m16) * 32 + q4 * 8;
    const int boff = (wn + m16) * 32 + q4 * 8;

    f32x4 acc[4][4];
#pragma unroll
    for (int i = 0; i < 4; i++)
#pragma unroll
        for (int j = 0; j < 4; j++) acc[i][j] = (f32x4){0.f, 0.f, 0.f, 0.f};

    for (int k0 = 0; k0 < K; k0 += 32) {
        __syncthreads();
        glds16(ga0 + k0, As + tid * 8);
        glds16(ga1 + k0, As + 2048 + tid * 8);
        glds16(gb0 + k0, Bs + tid * 8);
        glds16(gb1 + k0, Bs + 2048 + tid * 8);
        if constexpr (SPLIT) {
            glds16(gal0 + k0, AsL + tid * 8);
            glds16(gal1 + k0, AsL + 2048 + tid * 8);
            glds16(gbl0 + k0, BsL + tid * 8);
            glds16(gbl1 + k0, BsL + 2048 + tid * 8);
        }
        __syncthreads();

        f16x8 a[4], b[4], al[4], bl[4];
#pragma unroll
        for (int i = 0; i < 4; i++) a[i] = *(const f16x8*)(As + aoff + i * 512);
#pragma unroll
        for (int j = 0; j < 4; j++) b[j] = *(const f16x8*)(Bs + boff + j * 512);
        if constexpr (SPLIT) {
#pragma unroll
            for (int i = 0; i < 4; i++) al[i] = *(const f16x8*)(AsL + aoff + i * 512);
#pragma unroll
            for (int j = 0; j < 4; j++) bl[j] = *(const f16x8*)(BsL + boff + j * 512);
        }

#pragma unroll
        for (int i = 0; i < 4; i++)
#pragma unroll
            for (int j = 0; j < 4; j++) {
                if constexpr (SPLIT) {
                    acc[i][j] = __builtin_amdgcn_mfma_f32_16x16x32_f16(al[i], b[j], acc[i][j], 0, 0, 0);
                    acc[i][j] = __builtin_amdgcn_mfma_f32_16x16x32_f16(a[i], bl[j], acc[i][j], 0, 0, 0);
                }
                acc[i][j] = __builtin_amdgcn_mfma_f32_16x16x32_f16(a[i], b[j], acc[i][j], 0, 0, 0);
            }
    }

    float cs[4] = {0.f, 0.f, 0.f, 0.f};
    if constexpr (OUTMODE == 1) {
#pragma unroll
        for (int j = 0; j < 4; j++) cs[j] = colscale[n0 + wn + j * 16 + m16];
    }
#pragma unroll
    for (int i = 0; i < 4; i++) {
        const int rowb = m0 + wm + i * 16 + q4 * 4;
#pragma unroll
        for (int j = 0; j < 4; j++) {
            const int col = n0 + wn + j * 16 + m16;
#pragma unroll
            for (int rr = 0; rr < 4; rr++) {
                const float v = acc[i][j][rr];
                const size_t o = (size_t)(rowb + rr) * (size_t)N + col;
                if constexpr (OUTMODE == 0) { of32[o] = v; of16[o] = (f16)v; }
                else if constexpr (OUTMODE == 1) { obf16[o] = f32_to_bf16(v * cs[j]); }
                else if constexpr (OUTMODE == 2) { of16[o] = (f16)v; }
                else { of32[o] = v; }
            }
        }
    }
}

// ---------- per-(row, 4096-chunk) exact top-8 of bf16 sims ----------
__global__ __launch_bounds__(256) void k_chunk_top8(const unsigned short* __restrict__ sim,
                                                    float* __restrict__ cv, int* __restrict__ ci) {
    const int ch = blockIdx.x, b = blockIdx.y, t = threadIdx.x;
    const unsigned short* p = sim + (size_t)b * N_DIM + ch * 4096;
    float v[16];
#pragma unroll
    for (int i = 0; i < 16; i++) {
        unsigned int u = (unsigned int)p[t + i * 256] << 16;
        v[i] = __builtin_bit_cast(float, u);
    }
    __shared__ float lv[256];
    __shared__ int li[256];
    const int outbase = (b * 16 + ch) * 8;
    for (int it = 0; it < 8; ++it) {
        float bm = -1e30f; int bi = 0;
#pragma unroll
        for (int i = 0; i < 16; i++)
            if (v[i] > bm) { bm = v[i]; bi = i; }
        lv[t] = bm; li[t] = (t << 4) | bi;
        __syncthreads();
        for (int s = 128; s > 0; s >>= 1) {
            if (t < s && lv[t + s] > lv[t]) { lv[t] = lv[t + s]; li[t] = li[t + s]; }
            __syncthreads();
        }
        const int win = li[0];
        if (t == 0) {
            cv[outbase + it] = lv[0];
            ci[outbase + it] = ch * 4096 + (win >> 4) + (win & 15) * 256;
        }
        if ((win >> 4) == t) v[win & 15] = -1e30f;
        __syncthreads();
    }
}

// ---------- merge 128 candidates -> top-16 by value; fp32 rescore; exact top-8 + softmax ----------
__global__ __launch_bounds__(256) void k_merge_rescore(const float* __restrict__ cv, const int* __restrict__ ci,
                                                       const float* __restrict__ qn,
                                                       const float* __restrict__ keys32,
                                                       const float* __restrict__ sscale,
                                                       float* __restrict__ attn, int* __restrict__ aidx) {
    const int b = blockIdx.x, t = threadIdx.x;
    __shared__ float lv[128];
    __shared__ int li[128];
    __shared__ float rv[128];
    __shared__ int rsl[128];
    __shared__ int c16[16];
    __shared__ float rs[16];
    if (t < 128) { lv[t] = cv[b * 128 + t]; li[t] = ci[b * 128 + t]; }
    __syncthreads();
    for (int it = 0; it < 16; ++it) {
        if (t < 128) { rv[t] = lv[t]; rsl[t] = t; }
        __syncthreads();
        for (int s = 64; s > 0; s >>= 1) {
            if (t < s && rv[t + s] > rv[t]) { rv[t] = rv[t + s]; rsl[t] = rsl[t + s]; }
            __syncthreads();
        }
        if (t == 0) { int sl = rsl[0]; c16[it] = li[sl]; lv[sl] = -1e30f; }
        __syncthreads();
    }
    // rescore: group g of 16 lanes handles candidate g
    const int g = t >> 4, l16 = t & 15;
    const int idx = c16[g];
    const float* kr = keys32 + (size_t)idx * H_DIM;
    const float* qr = qn + (size_t)b * H_DIM;
    float sum = 0.f;
#pragma unroll 8
    for (int j = 0; j < 64; j++) {
        int k = l16 + j * 16;
        sum += qr[k] * kr[k];
    }
    for (int off = 8; off; off >>= 1) sum += __shfl_down(sum, off, 16);
    if (l16 == 0) rs[g] = sum * sscale[idx];
    __syncthreads();
    if (t == 0) {
        float v[16];
        for (int i = 0; i < 16; i++) v[i] = rs[i];
        float av[8]; int ai[8];
        for (int it = 0; it < 8; ++it) {
            float bm = -1e30f; int mi = 0;
            for (int i = 0; i < 16; i++)
                if (v[i] > bm) { bm = v[i]; mi = i; }
            av[it] = bm; ai[it] = c16[mi]; v[mi] = -1e30f;
        }
        float m = av[0], e[8], ssum = 0.f;
        for (int k = 0; k < 8; k++) { e[k] = expf(av[k] - m); ssum += e[k]; }
        for (int k = 0; k < 8; k++) {
            attn[b * 8 + k] = e[k] / ssum;
            aidx[b * 8 + k] = ai[k];
        }
    }
}

// ---------- s[b,:] = sum_k attn_k * store[idx_k,:]  (fp32 gather-combine, write fp16) ----------
__global__ __launch_bounds__(256) void k_combine(const float* __restrict__ store,
                                                 const float* __restrict__ attn, const int* __restrict__ aidx,
                                                 f16* __restrict__ s16) {
    const int b = blockIdx.x, t = threadIdx.x;
    __shared__ float a8[8];
    __shared__ int i8[8];
    if (t < 8) { a8[t] = attn[b * 8 + t]; i8[t] = aidx[b * 8 + t]; }
    __syncthreads();
#pragma unroll
    for (int p = 0; p < 4; p++) {
        const int col = t + p * 256;
        float sum = 0.f;
#pragma unroll
        for (int k = 0; k < 8; k++) sum += a8[k] * store[(size_t)i8[k] * H_DIM + col];
        s16[(size_t)b * H_DIM + col] = (f16)sum;
    }
}

// ---------- workspace layout (bytes) ----------
#define MB (1024ull * 1024ull)
#define OFF_STOREHI (0ull)              // 128 MB  } sim (bf16, 256 MB) reuses this
#define OFF_STORELO (128ull * MB)       // 128 MB  } region after keys GEMM is done
#define OFF_KEYS32  (256ull * MB)       // 256 MB
#define OFF_KEYS16  (512ull * MB)       // 128 MB
#define OFF_WKHI    (640ull * MB)       // 2 MB
#define OFF_WKLO    (642ull * MB)       // 2 MB
#define OFF_WV16    (644ull * MB)       // 2 MB
#define OFF_WO16    (646ull * MB)       // 2 MB
#define OFF_QN      (648ull * MB)       // 8 MB
#define OFF_Q16     (656ull * MB)       // 4 MB
#define OFF_W       (660ull * MB)       // 256 KB
#define OFF_SSCALE  (660ull * MB + 256ull * 1024ull)
#define OFF_SUMW    (660ull * MB + 512ull * 1024ull)
#define OFF_CV      (661ull * MB)       // 1 MB
#define OFF_CI      (662ull * MB)       // 1 MB
#define OFF_ATTN    (663ull * MB)       // 64 KB
#define OFF_AIDX    (663ull * MB + 64ull * 1024ull)
#define OFF_S16     (664ull * MB)       // 4 MB
#define OFF_T16     (668ull * MB)       // 4 MB

extern "C" void kernel_launch(void* const* d_in, const int* in_sizes, int n_in,
                              void* d_out, int out_size, void* d_ws, size_t ws_size,
                              hipStream_t stream) {
    const float* q     = (const float*)d_in[0];
    const float* store = (const float*)d_in[1];
    const float* imp   = (const float*)d_in[2];
    const float* ts    = (const float*)d_in[3];
    const float* Wk    = (const float*)d_in[4];
    const float* Wv    = (const float*)d_in[5];
    const float* Wo    = (const float*)d_in[6];
    float* out = (float*)d_out;
    char* ws = (char*)d_ws;

    f16* storeHi = (f16*)(ws + OFF_STOREHI);
    f16* storeLo = (f16*)(ws + OFF_STORELO);
    float* keys32 = (float*)(ws + OFF_KEYS32);
    f16* keys16 = (f16*)(ws + OFF_KEYS16);
    f16* wkHi = (f16*)(ws + OFF_WKHI);
    f16* wkLo = (f16*)(ws + OFF_WKLO);
    f16* wv16 = (f16*)(ws + OFF_WV16);
    f16* wo16 = (f16*)(ws + OFF_WO16);
    float* qn = (float*)(ws + OFF_QN);
    f16* q16 = (f16*)(ws + OFF_Q16);
    float* wbuf = (float*)(ws + OFF_W);
    float* sscale = (float*)(ws + OFF_SSCALE);
    float* sumw = (float*)(ws + OFF_SUMW);
    float* cv = (float*)(ws + OFF_CV);
    int* ci = (int*)(ws + OFF_CI);
    float* attn = (float*)(ws + OFF_ATTN);
    int* aidx = (int*)(ws + OFF_AIDX);
    f16* s16 = (f16*)(ws + OFF_S16);
    f16* t16 = (f16*)(ws + OFF_T16);
    unsigned short* sim = (unsigned short*)(ws + OFF_STOREHI);  // reuse store hi/lo region

    hipMemsetAsync(sumw, 0, 4, stream);

    // prep
    k_weights<<<N_DIM / 256, 256, 0, stream>>>(imp, ts, wbuf, sumw);
    k_split<<<(N_DIM * H_DIM) / 1024, 256, 0, stream>>>(store, storeHi, storeLo);
    k_split<<<(H_DIM * H_DIM) / 1024, 256, 0, stream>>>(Wk, wkHi, wkLo);
    k_tohalf<<<(H_DIM * H_DIM) / 1024, 256, 0, stream>>>(Wv, wv16);
    k_tohalf<<<(H_DIM * H_DIM) / 1024, 256, 0, stream>>>(Wo, wo16);
    k_qnorm<<<B_DIM, 256, 0, stream>>>(q, qn, q16);

    // keys = store @ Wk.T  (split fp16 -> ~fp32 accuracy), writes fp32 + fp16
    k_gemm<true, 0><<<dim3(H_DIM / 128, N_DIM / 128), 256, 0, stream>>>(
        storeHi, storeLo, wkHi, wkLo, H_DIM, keys32, keys16, nullptr, nullptr, H_DIM);

    // per-row scale = w_n / ((sumw+1e-8)*||keys_n||)
    k_rowstats<<<N_DIM, 256, 0, stream>>>(keys32, wbuf, sumw, sscale);

    // sim = (q16 @ keys16.T) * sscale[col] -> bf16 (selection only; overwrites store hi/lo region)
    k_gemm<false, 1><<<dim3(N_DIM / 128, B_DIM / 128), 256, 0, stream>>>(
        q16, nullptr, keys16, nullptr, H_DIM, nullptr, nullptr, sim, sscale, N_DIM);

    // candidates: top-8 per 4096-chunk, then global top-16, fp32 rescore, top-8 + softmax
    k_chunk_top8<<<dim3(16, B_DIM), 256, 0, stream>>>(sim, cv, ci);
    k_merge_rescore<<<B_DIM, 256, 0, stream>>>(cv, ci, qn, keys32, sscale, attn, aidx);

    // combine store rows, then (s @ Wv.T) @ Wo.T
    k_combine<<<B_DIM, 256, 0, stream>>>(store, attn, aidx, s16);
    k_gemm<false, 2><<<dim3(H_DIM / 128, B_DIM / 128), 256, 0, stream>>>(
        s16, nullptr, wv16, nullptr, H_DIM, nullptr, t16, nullptr, nullptr, H_DIM);
    k_gemm<false, 3><<<dim3(H_DIM / 128, B_DIM / 128), 256, 0, stream>>>(
        t16, nullptr, wo16, nullptr, H_DIM, out, nullptr, nullptr, nullptr, H_DIM);

    (void)in_sizes; (void)n_in; (void)out_size; (void)ws_size;
}

// Round 2
// 1558.635 us; speedup vs baseline: 1.0688x; 1.0688x over previous
//
#include <hip/hip_runtime.h>
#include <stdint.h>

// ---------- types ----------
typedef _Float16 f16;
typedef _Float16 f16x8 __attribute__((ext_vector_type(8)));
typedef _Float16 f16x4 __attribute__((ext_vector_type(4)));
typedef float    f32x4 __attribute__((ext_vector_type(4)));

#define B_DIM 2048
#define N_DIM 65536
#define H_DIM 1024

__device__ __forceinline__ unsigned short f32_to_bf16(float f) {
    unsigned int u = __builtin_bit_cast(unsigned int, f);
    unsigned int r = u + 0x7fffu + ((u >> 16) & 1u);
    return (unsigned short)(r >> 16);
}

typedef const __attribute__((address_space(1))) void g_void;
typedef __attribute__((address_space(3))) void l_void;
__device__ __forceinline__ void glds16(const void* g, void* l) {
    __builtin_amdgcn_global_load_lds((g_void*)g, (l_void*)l, 16, 0, 0);
}

// ---------- small prep kernels ----------
__global__ __launch_bounds__(256) void k_weights(const float* __restrict__ imp,
                                                 const float* __restrict__ ts,
                                                 float* __restrict__ w,
                                                 float* __restrict__ sumw) {
    int i = blockIdx.x * 256 + threadIdx.x;
    float age = 1.0f - ts[i];
    float r = expf(-fabsf(age) * (float)(1.0 - 0.99));
    float wv = r * (imp[i] + 1.0f);
    w[i] = wv;
    for (int off = 32; off; off >>= 1) wv += __shfl_down(wv, off, 64);
    __shared__ float ps[4];
    if ((threadIdx.x & 63) == 0) ps[threadIdx.x >> 6] = wv;
    __syncthreads();
    if (threadIdx.x == 0) atomicAdd(sumw, ps[0] + ps[1] + ps[2] + ps[3]);
}

// split fp32 -> fp16 hi + fp16 lo (8 floats/thread, 16B stores)
__global__ __launch_bounds__(256) void k_split(const float* __restrict__ x,
                                               f16* __restrict__ hi, f16* __restrict__ lo) {
    size_t i = (size_t)blockIdx.x * 256 + threadIdx.x;
    float4 v0 = ((const float4*)x)[2 * i];
    float4 v1 = ((const float4*)x)[2 * i + 1];
    float vv[8] = {v0.x, v0.y, v0.z, v0.w, v1.x, v1.y, v1.z, v1.w};
    f16x8 h, l;
#pragma unroll
    for (int j = 0; j < 8; j++) { h[j] = (f16)vv[j]; l[j] = (f16)(vv[j] - (float)h[j]); }
    ((f16x8*)hi)[i] = h;
    ((f16x8*)lo)[i] = l;
}

__global__ __launch_bounds__(256) void k_tohalf(const float* __restrict__ x, f16* __restrict__ h) {
    size_t i = (size_t)blockIdx.x * 256 + threadIdx.x;
    float4 v0 = ((const float4*)x)[2 * i];
    float4 v1 = ((const float4*)x)[2 * i + 1];
    f16x8 o = {(f16)v0.x, (f16)v0.y, (f16)v0.z, (f16)v0.w,
               (f16)v1.x, (f16)v1.y, (f16)v1.z, (f16)v1.w};
    ((f16x8*)h)[i] = o;
}

// q row-normalize -> fp32 + fp16
__global__ __launch_bounds__(256) void k_qnorm(const float* __restrict__ q,
                                               float* __restrict__ qn, f16* __restrict__ q16) {
    int b = blockIdx.x, t = threadIdx.x;
    float4 v = ((const float4*)(q + (size_t)b * H_DIM))[t];
    float ss = v.x * v.x + v.y * v.y + v.z * v.z + v.w * v.w;
    for (int off = 32; off; off >>= 1) ss += __shfl_down(ss, off, 64);
    __shared__ float ps[4];
    if ((t & 63) == 0) ps[t >> 6] = ss;
    __syncthreads();
    float tot = ps[0] + ps[1] + ps[2] + ps[3];
    float rn = 1.0f / fmaxf(sqrtf(tot), 1e-12f);
    float4 o;
    o.x = v.x * rn; o.y = v.y * rn; o.z = v.z * rn; o.w = v.w * rn;
    ((float4*)(qn + (size_t)b * H_DIM))[t] = o;
    f16x4 h = {(f16)o.x, (f16)o.y, (f16)o.z, (f16)o.w};
    ((f16x4*)(q16 + (size_t)b * H_DIM))[t] = h;
}

// per-key-row: sscale[n] = w[n] / ((sumw+1e-8) * max(||keys_n||,1e-12))
__global__ __launch_bounds__(256) void k_rowstats(const float* __restrict__ keys,
                                                  const float* __restrict__ w,
                                                  const float* __restrict__ sumw,
                                                  float* __restrict__ sscale) {
    int n = blockIdx.x, t = threadIdx.x;
    float4 v = ((const float4*)(keys + (size_t)n * H_DIM))[t];
    float ss = v.x * v.x + v.y * v.y + v.z * v.z + v.w * v.w;
    for (int off = 32; off; off >>= 1) ss += __shfl_down(ss, off, 64);
    __shared__ float ps[4];
    if ((t & 63) == 0) ps[t >> 6] = ss;
    __syncthreads();
    if (t == 0) {
        float tot = ps[0] + ps[1] + ps[2] + ps[3];
        sscale[n] = w[n] / ((sumw[0] + 1e-8f) * fmaxf(sqrtf(tot), 1e-12f));
    }
}

// ---------- GEMM: C[M,N] = A[M,K] * B[N,K]^T ; 128x128 tile, 4 waves, 16x16x32 f16 MFMA ----------
// OUTMODE 0: write fp32 + fp16            (keys)
// OUTMODE 1: write bf16 of v*colscale[col](sim)
// XM: blockIdx.x indexes M-tiles (fast dim shares B-tile for L2 reuse)
template <bool SPLIT, int OUTMODE, bool XM>
__global__ __launch_bounds__(256) void k_gemm(const f16* __restrict__ Ah, const f16* __restrict__ Al,
                                              const f16* __restrict__ Bh, const f16* __restrict__ Bl,
                                              const int K,
                                              float* __restrict__ of32, f16* __restrict__ of16,
                                              unsigned short* __restrict__ obf16,
                                              const float* __restrict__ colscale,
                                              const int N) {
    __shared__ f16 As[128 * 32];
    __shared__ f16 Bs[128 * 32];
    __shared__ f16 AsL[128 * 32];
    __shared__ f16 BsL[128 * 32];

    const int tid = threadIdx.x;
    const int m0 = (XM ? blockIdx.x : blockIdx.y) * 128;
    const int n0 = (XM ? blockIdx.y : blockIdx.x) * 128;
    const int r = tid >> 2, c8 = (tid & 3) * 8;

    const f16* ga0 = Ah + (size_t)(m0 + r) * K + c8;
    const f16* ga1 = Ah + (size_t)(m0 + r + 64) * K + c8;
    const f16* gb0 = Bh + (size_t)(n0 + r) * K + c8;
    const f16* gb1 = Bh + (size_t)(n0 + r + 64) * K + c8;
    const f16 *gal0 = nullptr, *gal1 = nullptr, *gbl0 = nullptr, *gbl1 = nullptr;
    if constexpr (SPLIT) {
        gal0 = Al + (size_t)(m0 + r) * K + c8;
        gal1 = Al + (size_t)(m0 + r + 64) * K + c8;
        gbl0 = Bl + (size_t)(n0 + r) * K + c8;
        gbl1 = Bl + (size_t)(n0 + r + 64) * K + c8;
    }

    const int lane = tid & 63, wave = tid >> 6;
    const int wm = (wave >> 1) * 64, wn = (wave & 1) * 64;
    const int q4 = lane >> 4, m16 = lane & 15;
    const int aoff = (wm + m16) * 32 + q4 * 8;
    const int boff = (wn + m16) * 32 + q4 * 8;

    f32x4 acc[4][4];
#pragma unroll
    for (int i = 0; i < 4; i++)
#pragma unroll
        for (int j = 0; j < 4; j++) acc[i][j] = (f32x4){0.f, 0.f, 0.f, 0.f};

    for (int k0 = 0; k0 < K; k0 += 32) {
        __syncthreads();
        glds16(ga0 + k0, As + tid * 8);
        glds16(ga1 + k0, As + 2048 + tid * 8);
        glds16(gb0 + k0, Bs + tid * 8);
        glds16(gb1 + k0, Bs + 2048 + tid * 8);
        if constexpr (SPLIT) {
            glds16(gal0 + k0, AsL + tid * 8);
            glds16(gal1 + k0, AsL + 2048 + tid * 8);
            glds16(gbl0 + k0, BsL + tid * 8);
            glds16(gbl1 + k0, BsL + 2048 + tid * 8);
        }
        __syncthreads();

        f16x8 a[4], b[4], al[4], bl[4];
#pragma unroll
        for (int i = 0; i < 4; i++) a[i] = *(const f16x8*)(As + aoff + i * 512);
#pragma unroll
        for (int j = 0; j < 4; j++) b[j] = *(const f16x8*)(Bs + boff + j * 512);
        if constexpr (SPLIT) {
#pragma unroll
            for (int i = 0; i < 4; i++) al[i] = *(const f16x8*)(AsL + aoff + i * 512);
#pragma unroll
            for (int j = 0; j < 4; j++) bl[j] = *(const f16x8*)(BsL + boff + j * 512);
        }

#pragma unroll
        for (int i = 0; i < 4; i++)
#pragma unroll
            for (int j = 0; j < 4; j++) {
                if constexpr (SPLIT) {
                    acc[i][j] = __builtin_amdgcn_mfma_f32_16x16x32_f16(al[i], b[j], acc[i][j], 0, 0, 0);
                    acc[i][j] = __builtin_amdgcn_mfma_f32_16x16x32_f16(a[i], bl[j], acc[i][j], 0, 0, 0);
                }
                acc[i][j] = __builtin_amdgcn_mfma_f32_16x16x32_f16(a[i], b[j], acc[i][j], 0, 0, 0);
            }
    }

    float cs[4] = {0.f, 0.f, 0.f, 0.f};
    if constexpr (OUTMODE == 1) {
#pragma unroll
        for (int j = 0; j < 4; j++) cs[j] = colscale[n0 + wn + j * 16 + m16];
    }
#pragma unroll
    for (int i = 0; i < 4; i++) {
        const int rowb = m0 + wm + i * 16 + q4 * 4;
#pragma unroll
        for (int j = 0; j < 4; j++) {
            const int col = n0 + wn + j * 16 + m16;
#pragma unroll
            for (int rr = 0; rr < 4; rr++) {
                const float v = acc[i][j][rr];
                const size_t o = (size_t)(rowb + rr) * (size_t)N + col;
                if constexpr (OUTMODE == 0) { of32[o] = v; of16[o] = (f16)v; }
                else if constexpr (OUTMODE == 1) { obf16[o] = f32_to_bf16(v * cs[j]); }
            }
        }
    }
}

// ---------- small GEMM: C[2048,1024] = A[2048,1024] * B[1024,1024]^T ; 64x128 tile ----------
// OUTMODE 2: fp16 out, OUTMODE 3: fp32 out
template <int OUTMODE>
__global__ __launch_bounds__(256) void k_gemm64(const f16* __restrict__ A, const f16* __restrict__ B,
                                                float* __restrict__ of32, f16* __restrict__ of16) {
    __shared__ f16 As[64 * 32];
    __shared__ f16 Bs[128 * 32];
    const int tid = threadIdx.x;
    const int m0 = blockIdx.y * 64, n0 = blockIdx.x * 128;
    const int r = tid >> 2, c8 = (tid & 3) * 8;
    const f16* ga = A + (size_t)(m0 + r) * H_DIM + c8;
    const f16* gb0 = B + (size_t)(n0 + r) * H_DIM + c8;
    const f16* gb1 = B + (size_t)(n0 + r + 64) * H_DIM + c8;

    const int lane = tid & 63, wave = tid >> 6;
    const int wn = wave * 32;
    const int q4 = lane >> 4, m16 = lane & 15;
    const int aoff = m16 * 32 + q4 * 8;
    const int boff = (wn + m16) * 32 + q4 * 8;

    f32x4 acc[4][2];
#pragma unroll
    for (int i = 0; i < 4; i++)
#pragma unroll
        for (int j = 0; j < 2; j++) acc[i][j] = (f32x4){0.f, 0.f, 0.f, 0.f};

    for (int k0 = 0; k0 < H_DIM; k0 += 32) {
        __syncthreads();
        glds16(ga + k0, As + tid * 8);
        glds16(gb0 + k0, Bs + tid * 8);
        glds16(gb1 + k0, Bs + 2048 + tid * 8);
        __syncthreads();
        f16x8 a[4], b[2];
#pragma unroll
        for (int i = 0; i < 4; i++) a[i] = *(const f16x8*)(As + aoff + i * 512);
#pragma unroll
        for (int j = 0; j < 2; j++) b[j] = *(const f16x8*)(Bs + boff + j * 512);
#pragma unroll
        for (int i = 0; i < 4; i++)
#pragma unroll
            for (int j = 0; j < 2; j++)
                acc[i][j] = __builtin_amdgcn_mfma_f32_16x16x32_f16(a[i], b[j], acc[i][j], 0, 0, 0);
    }

#pragma unroll
    for (int i = 0; i < 4; i++) {
        const int rowb = m0 + i * 16 + q4 * 4;
#pragma unroll
        for (int j = 0; j < 2; j++) {
            const int col = n0 + wn + j * 16 + m16;
#pragma unroll
            for (int rr = 0; rr < 4; rr++) {
                const float v = acc[i][j][rr];
                const size_t o = (size_t)(rowb + rr) * H_DIM + col;
                if constexpr (OUTMODE == 2) of16[o] = (f16)v;
                else of32[o] = v;
            }
        }
    }
}

// ---------- per-(row, 4096-chunk) exact top-8 via packed uint32 max-reduce ----------
// packed: monotone_bf16_key << 16 | elem_idx_in_chunk (12 bits)
__global__ __launch_bounds__(256) void k_chunk_top8(const unsigned short* __restrict__ sim,
                                                    unsigned int* __restrict__ ck) {
    const int ch = blockIdx.x, b = blockIdx.y, t = threadIdx.x;
    const unsigned short* p = sim + (size_t)b * N_DIM + (size_t)ch * 4096 + t * 16;
    uint4 d0 = ((const uint4*)p)[0];
    uint4 d1 = ((const uint4*)p)[1];
    unsigned int raw[8] = {d0.x, d0.y, d0.z, d0.w, d1.x, d1.y, d1.z, d1.w};
    unsigned int key[16];
#pragma unroll
    for (int i = 0; i < 8; i++) {
        unsigned int lo16 = raw[i] & 0xFFFFu, hi16 = raw[i] >> 16;
        lo16 ^= (lo16 & 0x8000u) ? 0xFFFFu : 0x8000u;
        hi16 ^= (hi16 & 0x8000u) ? 0xFFFFu : 0x8000u;
        key[2 * i]     = (lo16 << 16) | (unsigned)(t * 16 + 2 * i);
        key[2 * i + 1] = (hi16 << 16) | (unsigned)(t * 16 + 2 * i + 1);
    }
    unsigned int lm = 0;
#pragma unroll
    for (int i = 0; i < 16; i++) lm = max(lm, key[i]);

    __shared__ unsigned int wmax[2][4];
    const int w = t >> 6;
    unsigned int* outp = ck + (size_t)(b * 16 + ch) * 8;
    for (int rnd = 0; rnd < 8; ++rnd) {
        unsigned int u = lm;
        for (int off = 32; off; off >>= 1) u = max(u, __shfl_down(u, off, 64));
        if ((t & 63) == 0) wmax[rnd & 1][w] = u;
        __syncthreads();
        unsigned int win = max(max(wmax[rnd & 1][0], wmax[rnd & 1][1]),
                               max(wmax[rnd & 1][2], wmax[rnd & 1][3]));
        if (t == 0) outp[rnd] = win;
        if (((win & 0xFFFu) >> 4) == (unsigned)t) {
            key[win & 15u] = 0;
            lm = 0;
#pragma unroll
            for (int i = 0; i < 16; i++) lm = max(lm, key[i]);
        }
    }
}

// ---------- merge 128 cands -> top-16; fp32 rescore; top-8 + softmax; gather-combine ----------
__global__ __launch_bounds__(256) void k_merge(const unsigned int* __restrict__ ck,
                                               const float* __restrict__ qn,
                                               const float* __restrict__ keys32,
                                               const float* __restrict__ sscale,
                                               const float* __restrict__ store,
                                               f16* __restrict__ s16) {
    const int b = blockIdx.x, t = threadIdx.x;
    __shared__ unsigned int cks[128];
    __shared__ unsigned int wmax2[2][2];
    __shared__ int c16[16];
    __shared__ float rs[16];
    __shared__ float a8[8];
    __shared__ int i8[8];

    if (t < 128) cks[t] = ck[(size_t)b * 128 + t];
    __syncthreads();
    unsigned int r2 = (t < 128) ? ((cks[t] & 0xFFFF0000u) | (unsigned)t) : 0u;

    for (int rnd = 0; rnd < 16; ++rnd) {
        unsigned int u = r2;
        for (int off = 32; off; off >>= 1) u = max(u, __shfl_down(u, off, 64));
        if ((t & 63) == 0 && t < 128) wmax2[rnd & 1][t >> 6] = u;
        __syncthreads();
        unsigned int win = max(wmax2[rnd & 1][0], wmax2[rnd & 1][1]);
        int j = (int)(win & 127u);
        if (t == 0) c16[rnd] = (j >> 3) * 4096 + (int)(cks[j] & 0xFFFu);
        if (t == j) r2 = 0;
    }
    __syncthreads();

    // fp32 rescore: group g (16 lanes) handles candidate g
    const int g = t >> 4, l16 = t & 15;
    const int idx = c16[g];
    const float* kr = keys32 + (size_t)idx * H_DIM;
    const float* qr = qn + (size_t)b * H_DIM;
    float sum = 0.f;
#pragma unroll 8
    for (int j = 0; j < 64; j++) {
        int k = l16 + j * 16;
        sum += qr[k] * kr[k];
    }
    for (int off = 8; off; off >>= 1) sum += __shfl_down(sum, off, 16);
    if (l16 == 0) rs[g] = sum * sscale[idx];
    __syncthreads();

    if (t == 0) {
        float v[16];
        for (int i = 0; i < 16; i++) v[i] = rs[i];
        float av[8]; int ai[8];
        for (int it = 0; it < 8; ++it) {
            float bm = -1e30f; int mi = 0;
            for (int i = 0; i < 16; i++)
                if (v[i] > bm) { bm = v[i]; mi = i; }
            av[it] = bm; ai[it] = c16[mi]; v[mi] = -1e30f;
        }
        float m = av[0], e[8], ssum = 0.f;
        for (int k = 0; k < 8; k++) { e[k] = expf(av[k] - m); ssum += e[k]; }
        for (int k = 0; k < 8; k++) { a8[k] = e[k] / ssum; i8[k] = ai[k]; }
    }
    __syncthreads();

    // combine: s[b,:] = sum_k a8[k] * store[i8[k],:]
#pragma unroll
    for (int p = 0; p < 4; p++) {
        const int col = t + p * 256;
        float sum2 = 0.f;
#pragma unroll
        for (int k = 0; k < 8; k++) sum2 += a8[k] * store[(size_t)i8[k] * H_DIM + col];
        s16[(size_t)b * H_DIM + col] = (f16)sum2;
    }
}

// ---------- workspace layout (bytes) ----------
#define MB (1024ull * 1024ull)
#define OFF_STOREHI (0ull)              // 128 MB  } sim (bf16, 256 MB) reuses this
#define OFF_STORELO (128ull * MB)       // 128 MB  } region after keys GEMM is done
#define OFF_KEYS32  (256ull * MB)       // 256 MB
#define OFF_KEYS16  (512ull * MB)       // 128 MB
#define OFF_WKHI    (640ull * MB)       // 2 MB
#define OFF_WKLO    (642ull * MB)       // 2 MB
#define OFF_WV16    (644ull * MB)       // 2 MB
#define OFF_WO16    (646ull * MB)       // 2 MB
#define OFF_QN      (648ull * MB)       // 8 MB
#define OFF_Q16     (656ull * MB)       // 4 MB
#define OFF_W       (660ull * MB)       // 256 KB
#define OFF_SSCALE  (660ull * MB + 256ull * 1024ull)
#define OFF_SUMW    (660ull * MB + 512ull * 1024ull)
#define OFF_CK      (661ull * MB)       // 1 MB
#define OFF_S16     (664ull * MB)       // 4 MB
#define OFF_T16     (668ull * MB)       // 4 MB

extern "C" void kernel_launch(void* const* d_in, const int* in_sizes, int n_in,
                              void* d_out, int out_size, void* d_ws, size_t ws_size,
                              hipStream_t stream) {
    const float* q     = (const float*)d_in[0];
    const float* store = (const float*)d_in[1];
    const float* imp   = (const float*)d_in[2];
    const float* ts    = (const float*)d_in[3];
    const float* Wk    = (const float*)d_in[4];
    const float* Wv    = (const float*)d_in[5];
    const float* Wo    = (const float*)d_in[6];
    float* out = (float*)d_out;
    char* ws = (char*)d_ws;

    f16* storeHi = (f16*)(ws + OFF_STOREHI);
    f16* storeLo = (f16*)(ws + OFF_STORELO);
    float* keys32 = (float*)(ws + OFF_KEYS32);
    f16* keys16 = (f16*)(ws + OFF_KEYS16);
    f16* wkHi = (f16*)(ws + OFF_WKHI);
    f16* wkLo = (f16*)(ws + OFF_WKLO);
    f16* wv16 = (f16*)(ws + OFF_WV16);
    f16* wo16 = (f16*)(ws + OFF_WO16);
    float* qn = (float*)(ws + OFF_QN);
    f16* q16 = (f16*)(ws + OFF_Q16);
    float* wbuf = (float*)(ws + OFF_W);
    float* sscale = (float*)(ws + OFF_SSCALE);
    float* sumw = (float*)(ws + OFF_SUMW);
    unsigned int* ck = (unsigned int*)(ws + OFF_CK);
    f16* s16 = (f16*)(ws + OFF_S16);
    f16* t16 = (f16*)(ws + OFF_T16);
    unsigned short* sim = (unsigned short*)(ws + OFF_STOREHI);  // reuse store hi/lo region

    hipMemsetAsync(sumw, 0, 4, stream);

    // prep
    k_weights<<<N_DIM / 256, 256, 0, stream>>>(imp, ts, wbuf, sumw);
    k_split<<<(N_DIM * H_DIM) / 2048, 256, 0, stream>>>(store, storeHi, storeLo);
    k_split<<<(H_DIM * H_DIM) / 2048, 256, 0, stream>>>(Wk, wkHi, wkLo);
    k_tohalf<<<(H_DIM * H_DIM) / 2048, 256, 0, stream>>>(Wv, wv16);
    k_tohalf<<<(H_DIM * H_DIM) / 2048, 256, 0, stream>>>(Wo, wo16);
    k_qnorm<<<B_DIM, 256, 0, stream>>>(q, qn, q16);

    // keys = store @ Wk.T  (split fp16 3-term -> ~fp32 accuracy), writes fp32 + fp16
    k_gemm<true, 0, false><<<dim3(H_DIM / 128, N_DIM / 128), 256, 0, stream>>>(
        storeHi, storeLo, wkHi, wkLo, H_DIM, keys32, keys16, nullptr, nullptr, H_DIM);

    // per-row scale = w_n / ((sumw+1e-8)*||keys_n||)
    k_rowstats<<<N_DIM, 256, 0, stream>>>(keys32, wbuf, sumw, sscale);

    // sim = (q16 @ keys16.T) * sscale[col] -> bf16; x = B-tiles (fast) so 16 blocks share a keys tile
    k_gemm<false, 1, true><<<dim3(B_DIM / 128, N_DIM / 128), 256, 0, stream>>>(
        q16, nullptr, keys16, nullptr, H_DIM, nullptr, nullptr, sim, sscale, N_DIM);

    // candidates: top-8 per 4096-chunk (packed), global top-16, fp32 rescore, top-8+softmax+combine
    k_chunk_top8<<<dim3(16, B_DIM), 256, 0, stream>>>(sim, ck);
    k_merge<<<B_DIM, 256, 0, stream>>>(ck, qn, keys32, sscale, store, s16);

    // (s @ Wv.T) @ Wo.T
    k_gemm64<2><<<dim3(H_DIM / 128, B_DIM / 64), 256, 0, stream>>>(s16, wv16, nullptr, t16);
    k_gemm64<3><<<dim3(H_DIM / 128, B_DIM / 64), 256, 0, stream>>>(t16, wo16, out, nullptr);

    (void)in_sizes; (void)n_in; (void)out_size; (void)ws_size;
}